// Round 9
// baseline (103.352 us; speedup 1.0000x reference)
//
#include <hip/hip_runtime.h>
#include <stdint.h>

using i32x4  = __attribute__((ext_vector_type(4))) int;
using i32x16 = __attribute__((ext_vector_type(16))) int;

// ---------------- ws layout ----------------
#define WS_SCALED   2048
#define WS_SCALEF   2056
#define WS_FACT     4096
#define WS_XQ       (1u << 20)
#define WS_QW       ((1u << 20) + (32u << 20))

// ---------------- kernel 1: fused aquant (blocks 0..8191) + wabs partials (8192..8447) ----
__device__ inline int q8pack(float4 f, float as) {
    int a = (int)fminf(fmaxf(rintf(f.x * as), -128.0f), 127.0f);
    int b = (int)fminf(fmaxf(rintf(f.y * as), -128.0f), 127.0f);
    int c = (int)fminf(fmaxf(rintf(f.z * as), -128.0f), 127.0f);
    int d = (int)fminf(fmaxf(rintf(f.w * as), -128.0f), 127.0f);
    return (a & 0xff) | ((b & 0xff) << 8) | ((c & 0xff) << 16) | ((d & 0xff) << 24);
}

__global__ __launch_bounds__(256) void k_fused1(const float* __restrict__ x,
                                                const float* __restrict__ w,
                                                int8_t* __restrict__ xq,
                                                float* __restrict__ fact,
                                                double* __restrict__ partials) {
    int t = threadIdx.x;
    if (blockIdx.x >= 8192) {
        int b = blockIdx.x - 8192;
        const float4* w4 = (const float4*)(w + b * 4096);
        double s = 0.0;
#pragma unroll
        for (int i = 0; i < 4; ++i) {
            float4 v = w4[i * 256 + t];
            s += (double)fabsf(v.x) + (double)fabsf(v.y) +
                 (double)fabsf(v.z) + (double)fabsf(v.w);
        }
#pragma unroll
        for (int off = 32; off > 0; off >>= 1) s += __shfl_down(s, off, 64);
        __shared__ double lds[4];
        if ((t & 63) == 0) lds[t >> 6] = s;
        __syncthreads();
        if (t == 0) partials[b] = ((lds[0] + lds[1]) + (lds[2] + lds[3]));
        return;
    }
    int wid = t >> 6;
    int lane = t & 63;
    int token = blockIdx.x * 4 + wid;
    const float* xr = x + (size_t)token * 1024;
    float4 v[4];
    float m = 0.0f;
#pragma unroll
    for (int c = 0; c < 4; ++c) {
        v[c] = *(const float4*)(xr + c * 256 + lane * 4);
        m = fmaxf(m, fmaxf(fmaxf(fabsf(v[c].x), fabsf(v[c].y)),
                           fmaxf(fabsf(v[c].z), fabsf(v[c].w))));
    }
#pragma unroll
    for (int off = 32; off > 0; off >>= 1) m = fmaxf(m, __shfl_xor(m, off, 64));
    m = fmaxf(m, 1e-5f);
    float as = 127.0f / m;
    int* xqo = (int*)xq;
#pragma unroll
    for (int c = 0; c < 4; ++c)
        xqo[token * 256 + c * 64 + lane] = q8pack(v[c], as);
    if (lane == 0) fact[token] = 1.0f / as;
}

// ---------------- kernel 2: fused scale-reduce (redundant, deterministic) + wquant ----
__global__ __launch_bounds__(256) void k_fused2(const float* __restrict__ w,
                                                const double* __restrict__ partials,
                                                int8_t* __restrict__ qw,
                                                float* __restrict__ scale_f) {
    int t = threadIdx.x;
    double s = partials[t];
#pragma unroll
    for (int off = 32; off > 0; off >>= 1) s += __shfl_down(s, off, 64);
    __shared__ double lds[4];
    if ((t & 63) == 0) lds[t >> 6] = s;
    __syncthreads();
    __shared__ double sc_sh;
    if (t == 0) {
        double m = ((lds[0] + lds[1]) + (lds[2] + lds[3])) / 1048576.0;
        if (m < 1e-5) m = 1e-5;
        sc_sh = m;
        if (blockIdx.x == 0) *scale_f = (float)m;
    }
    __syncthreads();
    double half_s = 0.5 * sc_sh;

    int idx = blockIdx.x * 2048 + t * 8;
    float4 v0 = *(const float4*)(w + idx);
    float4 v1 = *(const float4*)(w + idx + 4);
    float f[8] = {v0.x, v0.y, v0.z, v0.w, v1.x, v1.y, v1.z, v1.w};
    union { char c[8]; int2 p; } u;
#pragma unroll
    for (int i = 0; i < 8; ++i) {
        char q = 0;
        if ((double)fabsf(f[i]) > half_s) q = (f[i] > 0.0f) ? 1 : -1;
        u.c[i] = q;
    }
    *(int2*)(qw + idx) = u.p;
}

// ---------------- kernel 3: i8 GEMM, 128x256 tile, BK=32, reg-dbuf pipeline (fixed) ----
// 256 threads = 4 waves (1M x 4N), per-wave 128x64 = 4x2 of 32x32x32.
// 3 rotating LDS buffers (12 KB each). Per iter t:
//   stage(t+2) | vmcnt(3) | s_barrier | ds_read(t+1 -> bank nxt) |
//   MFMA(t, bank cur, no wait) | lgkmcnt(0)+sched_barrier(0).
// vmcnt BEFORE the barrier (per-wave counter -> barrier publishes all waves' loads).
// Write-after-read safe: tile t-1 reads drained by each wave's lgkmcnt(0) at end of
// iter t-2, which precedes barrier(t-1), which precedes any wave's iter-t stage.

__device__ __forceinline__ void gl_lds16(const void* g, void* l) {
    __builtin_amdgcn_global_load_lds((const __attribute__((address_space(1))) void*)g,
                                     (__attribute__((address_space(3))) void*)l, 16, 0, 0);
}

__global__ __launch_bounds__(256, 2) void k_gemm7(const int8_t* __restrict__ A,
                                                  const int8_t* __restrict__ B,
                                                  const float* __restrict__ fact,
                                                  const float* __restrict__ scale_f,
                                                  const float* __restrict__ bias,
                                                  float* __restrict__ out) {
    __shared__ int8_t smem[36864];          // 3 x (A 4096 | B 8192)

    const int tid  = threadIdx.x;
    const int lane = tid & 63;
    const int wn   = tid >> 6;              // 0..3
    const int l31  = lane & 31;
    const int l5   = lane >> 5;

    // XCD-aware bijective swizzle (1024 % 8 == 0)
    int bid = blockIdx.x;
    int swz = (bid & 7) * 128 + (bid >> 3);
    int tm = swz >> 2;                      // 0..255
    int tn = swz & 3;                       // 0..3

    const int8_t* Ag = A + (size_t)tm * 128 * 1024;
    const int8_t* Bg = B + (size_t)tn * 256 * 1024;

    // staging: thread tid covers LDS row tid>>1 (0..127), 16B-half tid&1
    const int srow = tid >> 1, ss = tid & 1;
    const int gsrc = srow * 1024 + ((ss ^ ((srow >> 2) & 1)) << 4);
    auto stage = [&](int buf, int kb) {
        int8_t* base = smem + buf * 12288;
        gl_lds16(Ag + gsrc + kb,          base + tid * 16);
        gl_lds16(Bg + gsrc + kb,          base + 4096 + tid * 16);
        gl_lds16(Bg + gsrc + 131072 + kb, base + 8192 + tid * 16);
    };

    // read: row = {mt|nt}*32 + l31 (+wn*64 for B); (row>>2)&1 == (l31>>2)&1
    const int rdoff = l31 * 32 + ((l5 ^ ((l31 >> 2) & 1)) << 4);
    auto ldA = [&](int buf, int mt) -> i32x4 {
        return *(const i32x4*)(smem + buf * 12288 + mt * 1024 + rdoff);
    };
    auto ldB = [&](int buf, int nt) -> i32x4 {
        return *(const i32x4*)(smem + buf * 12288 + 4096 + wn * 2048 + nt * 1024 + rdoff);
    };

    i32x16 acc[4][2];
#pragma unroll
    for (int i = 0; i < 4; ++i)
#pragma unroll
        for (int j = 0; j < 2; ++j)
#pragma unroll
            for (int k = 0; k < 16; ++k) acc[i][j][k] = 0;

    i32x4 aB[2][4], bB[2][2];

    // prologue: stage tiles 0,1; publish tile0; load bank0
    stage(0, 0);
    stage(1, 32);
    asm volatile("s_waitcnt vmcnt(3)" ::: "memory");   // my tile0 loads landed
    __builtin_amdgcn_s_barrier();                      // all waves' tile0 landed
    __builtin_amdgcn_sched_barrier(0);
#pragma unroll
    for (int mt = 0; mt < 4; ++mt) aB[0][mt] = ldA(0, mt);
#pragma unroll
    for (int nt = 0; nt < 2; ++nt) bB[0][nt] = ldB(0, nt);
    asm volatile("s_waitcnt lgkmcnt(0)" ::: "memory");
    __builtin_amdgcn_sched_barrier(0);

#pragma unroll
    for (int t = 0; t < 32; ++t) {
        const int cur = t & 1, nxt = cur ^ 1;

        if (t + 2 < 32) stage((t + 2) % 3, (t + 2) * 32);
        if (t < 30)       { asm volatile("s_waitcnt vmcnt(3)" ::: "memory"); }
        else if (t == 30) { asm volatile("s_waitcnt vmcnt(0)" ::: "memory"); }
        __builtin_amdgcn_s_barrier();       // publishes tile t+1 (all waves drained)
        __builtin_amdgcn_sched_barrier(0);

        if (t < 31) {
            const int nb = (t + 1) % 3;
#pragma unroll
            for (int mt = 0; mt < 4; ++mt) aB[nxt][mt] = ldA(nb, mt);
#pragma unroll
            for (int nt = 0; nt < 2; ++nt) bB[nxt][nt] = ldB(nb, nt);
        }
        __builtin_amdgcn_s_setprio(1);      // MFMAs on bank cur — independent of reads above
#pragma unroll
        for (int mt = 0; mt < 4; ++mt)
#pragma unroll
            for (int nt = 0; nt < 2; ++nt)
                acc[mt][nt] = __builtin_amdgcn_mfma_i32_32x32x32_i8(
                    aB[cur][mt], bB[cur][nt], acc[mt][nt], 0, 0, 0);
        __builtin_amdgcn_s_setprio(0);
        if (t < 31) {
            asm volatile("s_waitcnt lgkmcnt(0)" ::: "memory");   // bank nxt ready
            __builtin_amdgcn_sched_barrier(0);                   // rule #18 fence
        }
    }

    // ---- epilogue: direct stores ----
    const float sc = *scale_f;
#pragma unroll
    for (int mt = 0; mt < 4; ++mt) {
        int rbase = tm * 128 + mt * 32 + 4 * l5;
        float fr[16];
#pragma unroll
        for (int r = 0; r < 16; ++r)
            fr[r] = sc * fact[rbase + (r & 3) + 8 * (r >> 2)];
#pragma unroll
        for (int nt = 0; nt < 2; ++nt) {
            int c = tn * 256 + wn * 64 + nt * 32 + l31;
            float bv = bias[c];
#pragma unroll
            for (int r = 0; r < 16; ++r) {
                int row = rbase + (r & 3) + 8 * (r >> 2);
                out[(size_t)row * 1024 + c] = (float)acc[mt][nt][r] * fr[r] + bv;
            }
        }
    }
}

extern "C" void kernel_launch(void* const* d_in, const int* in_sizes, int n_in,
                              void* d_out, int out_size, void* d_ws, size_t ws_size,
                              hipStream_t stream) {
    const float* x    = (const float*)d_in[0];
    const float* w    = (const float*)d_in[1];
    const float* bias = (const float*)d_in[2];
    float* out = (float*)d_out;
    char* ws = (char*)d_ws;

    double* partials = (double*)ws;
    float*  scale_f  = (float*)(ws + WS_SCALEF);
    float*  fact     = (float*)(ws + WS_FACT);
    int8_t* xq       = (int8_t*)(ws + WS_XQ);
    int8_t* qw       = (int8_t*)(ws + WS_QW);

    k_fused1<<<8448, 256, 0, stream>>>(x, w, xq, fact, partials);
    k_fused2<<<512, 256, 0, stream>>>(w, partials, qw, scale_f);
    k_gemm7<<<1024, 256, 0, stream>>>(xq, qw, fact, scale_f, bias, out);
}